// Round 3
// baseline (12206.325 us; speedup 1.0000x reference)
//
#include <hip/hip_runtime.h>
#include <math.h>

// Problem constants
#define SB   64     // batch
#define SN   128    // seq len
#define SE   1024   // feature dim
#define SD   256    // hidden D
#define SD2  512    // 2D
#define SD3  768    // 3D
#define SIN  2048   // 4D+E
#define SNC  7
#define SBN  8192   // SB*SN
#define CS   16     // chunk steps for gate precompute

__device__ __forceinline__ float wsum(float v){
#pragma unroll
  for (int o = 32; o; o >>= 1) v += __shfl_xor(v, o);
  return v;
}
__device__ __forceinline__ float sigm(float x){ return 1.f/(1.f + expf(-x)); }

// ---------------------------------------------------------------------------
// Generic fp32 GEMM: C[M,N] = A @ op(B) (+bias)(+acc)(+relu), batched via z.
// BKMAJ=false: B rows are N (NT).  BKMAJ=true: B rows are K (NN).
// BM=128, BN=64, BK=16, 256 threads, 8x4 micro-tile. M%128==0, N%64==0, K%16==0.
// lda/ldb/ldc are row strides (elements); sA/sB/sC are per-z strides.
// ---------------------------------------------------------------------------
template<bool BKMAJ, bool BIAS, bool RELU, bool ACC>
__global__ __launch_bounds__(256)
void gemm_k(const float* __restrict__ A, const float* __restrict__ Bm,
            const float* __restrict__ bias, float* __restrict__ C,
            int Nn, int K, int lda, int ldb, int ldc,
            long sA, long sB, long sC)
{
  __shared__ float As[16][132];
  __shared__ float Bs[16][68];
  const int t  = threadIdx.x;
  const int tx = t & 15, ty = t >> 4;
  const float* Ab = A + (long)blockIdx.z * sA;
  const float* Bb = Bm + (long)blockIdx.z * sB;
  float* Cb = C + (long)blockIdx.z * sC;
  const int m0 = blockIdx.y * 128, n0 = blockIdx.x * 64;
  float acc[8][4];
#pragma unroll
  for (int i = 0; i < 8; ++i)
#pragma unroll
    for (int j = 0; j < 4; ++j) acc[i][j] = 0.f;

  const int am = t >> 1, ak = (t & 1) * 8;
  int bn_ = 0, bk_ = 0;
  if (BKMAJ) { bk_ = t >> 4; bn_ = (t & 15) * 4; }
  else       { bn_ = t >> 2; bk_ = (t & 3) * 4; }

  for (int k0 = 0; k0 < K; k0 += 16) {
    const float4 a0 = *(const float4*)(Ab + (long)(m0 + am) * lda + k0 + ak);
    const float4 a1 = *(const float4*)(Ab + (long)(m0 + am) * lda + k0 + ak + 4);
    float4 b0;
    if (BKMAJ) b0 = *(const float4*)(Bb + (long)(k0 + bk_) * ldb + n0 + bn_);
    else       b0 = *(const float4*)(Bb + (long)(n0 + bn_) * ldb + k0 + bk_);
    __syncthreads();
    As[ak+0][am] = a0.x; As[ak+1][am] = a0.y; As[ak+2][am] = a0.z; As[ak+3][am] = a0.w;
    As[ak+4][am] = a1.x; As[ak+5][am] = a1.y; As[ak+6][am] = a1.z; As[ak+7][am] = a1.w;
    if (BKMAJ) { *(float4*)&Bs[bk_][bn_] = b0; }
    else { Bs[bk_+0][bn_] = b0.x; Bs[bk_+1][bn_] = b0.y; Bs[bk_+2][bn_] = b0.z; Bs[bk_+3][bn_] = b0.w; }
    __syncthreads();
#pragma unroll
    for (int kk = 0; kk < 16; ++kk) {
      float av[8], bv[4];
      *(float4*)&av[0] = *(const float4*)&As[kk][ty*8];
      *(float4*)&av[4] = *(const float4*)&As[kk][ty*8+4];
      *(float4*)&bv[0] = *(const float4*)&Bs[kk][tx*4];
#pragma unroll
      for (int ii = 0; ii < 8; ++ii)
#pragma unroll
        for (int jj = 0; jj < 4; ++jj)
          acc[ii][jj] = fmaf(av[ii], bv[jj], acc[ii][jj]);
    }
  }
#pragma unroll
  for (int ii = 0; ii < 8; ++ii) {
#pragma unroll
    for (int jj = 0; jj < 4; ++jj) {
      float v = acc[ii][jj];
      if (BIAS) v += bias[n0 + tx*4 + jj];
      const long ci = (long)(m0 + ty*8 + ii) * ldc + n0 + tx*4 + jj;
      if (ACC) v += Cb[ci];
      if (RELU) v = fmaxf(v, 0.f);
      Cb[ci] = v;
    }
  }
}

// Htmp is b-major (row b*128+n). Write time-major X0f[(n*64+b)] and reversed
// X0r[((127-n)*64+b)].
__global__ void spread_k(const float* __restrict__ src, float* __restrict__ xf,
                         float* __restrict__ xr)
{
  const int r = blockIdx.x, t = threadIdx.x;   // src row = b*128+n
  const int b = r >> 7, n = r & 127;
  const float v = src[(long)r * SD + t];
  xf[((long)(n * 64 + b)) * SD + t] = v;
  xr[((long)((127 - n) * 64 + b)) * SD + t] = v;
}

// Pack per-layer GK weights: Wpk[cd] = [cwih(768x256); pwhh(768x256)],
// bpk[cd] = [cbih; pbhh]. Grid (1536, 4cd).
struct PkArgs {
  const float* wA[4]; const float* wB[4];
  const float* bA[4]; const float* bB[4];
  float* Wpk; float* bpk;
};
__global__ void pack_k(PkArgs a)
{
  const int cd = blockIdx.y, r = blockIdx.x, t = threadIdx.x;
  const float* src = (r < 768) ? (a.wA[cd] + (long)r * SD)
                               : (a.wB[cd] + (long)(r - 768) * SD);
  a.Wpk[((long)cd * 1536 + r) * SD + t] = src[t];
  if (t == 0) a.bpk[cd * 1536 + r] = (r < 768) ? a.bA[cd][r] : a.bB[cd][r - 768];
}

// S0[m] = Q[m,:] . bk
__global__ void s0_k(const float* __restrict__ Q, const float* __restrict__ bk,
                     float* __restrict__ S0)
{
  const int r = blockIdx.x * 4 + (threadIdx.x >> 6), lane = threadIdx.x & 63;
  const float4 q  = *(const float4*)(Q + (long)r * SD + lane * 4);
  const float4 kb = *(const float4*)(bk + lane * 4);
  float p = q.x*kb.x + q.y*kb.y + q.z*kb.z + q.w*kb.w;
  p = wsum(p);
  if (lane == 0) S0[r] = p;
}

// ---------------------------------------------------------------------------
// Step kernel 1: attention -> M.  One block per (cd, b). Time-major H1
// (row n at n*64*SD2, fwd/bwd column offset baked into the H1 pointer).
// ---------------------------------------------------------------------------
struct K1Args {
  const float* Qt[4]; const float* S0[4]; const float* H1[4];
  const int* adj[4]; int rev[4];
  float* M; int step;
};
__global__ __launch_bounds__(256) void k1_attn(K1Args a)
{
  const int cd = blockIdx.x >> 6, b = blockIdx.x & 63;
  const int i = a.step, t = threadIdx.x, lane = t & 63, wv = t >> 6;
  float* Mout = a.M + (cd * 64 + b) * SD;
  if (i == 0) { Mout[t] = 0.f; return; }
  __shared__ float lg[SN];
  __shared__ float wgt[SN];
  const float* H1p = a.H1[cd] + (long)b * SD2;
  const float* qp  = a.Qt[cd] + (long)(i * 64 + b) * SD;
  const float4 q4 = *(const float4*)(qp + lane * 4);
  const float s0 = a.S0[cd][i * 64 + b];
  const int* adjp = a.adj[cd];
  const int rev = a.rev[cd];
  for (int n = wv; n < i; n += 4) {
    const float4 h4 = *(const float4*)(H1p + (long)n * (64 * SD2) + lane * 4);
    float p = q4.x*h4.x + q4.y*h4.y + q4.z*h4.z + q4.w*h4.w;
    p = wsum(p);
    if (lane == 0) {
      const int ii = rev ? (SN - 1 - i) : i;
      const int nn = rev ? (SN - 1 - n) : n;
      const float aa = (float)adjp[((long)b * SN + ii) * SN + nn];
      lg[n] = p + s0 - (1.f - aa) * 1e30f;
    }
  }
  __syncthreads();
  if (wv == 0) {
    const float v0 = (lane      < i) ? lg[lane]      : -3.0e38f;
    const float v1 = (lane + 64 < i) ? lg[lane + 64] : -3.0e38f;
    float mx = fmaxf(v0, v1);
#pragma unroll
    for (int o = 32; o; o >>= 1) mx = fmaxf(mx, __shfl_xor(mx, o));
    const float e0 = (lane      < i) ? expf(v0 - mx) : 0.f;
    const float e1 = (lane + 64 < i) ? expf(v1 - mx) : 0.f;
    float s = e0 + e1;
#pragma unroll
    for (int o = 32; o; o >>= 1) s += __shfl_xor(s, o);
    const float inv = 1.f / s;
    if (lane      < i) wgt[lane]      = e0 * inv;
    if (lane + 64 < i) wgt[lane + 64] = e1 * inv;
  }
  __syncthreads();
  float acc = 0.f;
  for (int n = 0; n < i; ++n) acc = fmaf(wgt[n], H1p[(long)n * (64 * SD2) + t], acc);
  Mout[t] = acc;
}

// ---------------------------------------------------------------------------
// Step kernel 2: gates GEMM + GRU elementwise + write H1 row i (time-major).
// Grid (64 colblocks x 4 cd). Block: 4 output cols (24 gate rows) x 64 b.
// ---------------------------------------------------------------------------
struct K2Args {
  const float* M;
  const float* Wc[4]; const float* Wp[4];   // cwhh, pwih (768x256)
  const float* bc[4]; const float* bp[4];   // cbhh, pbih
  const float* GK[4];                       // chunk 1024x1536: [giC(768)|ghP(768)]
  const float* X[4];                        // pass input (time-major, ldX)
  float* H1[4];                             // time-major stride SD2, col-offset baked
  int ldX, step, s0;
};
__global__ __launch_bounds__(256) void k2_gates(K2Args a)
{
  const int cd = blockIdx.y, j0 = blockIdx.x * 4, i = a.step;
  const int t = threadIdx.x, b = t & 63, q = t >> 6;
  __shared__ float Ms[64 * 130];
  __shared__ float red[24 * 64 * 4];
  const float* Mp = a.M + cd * 64 * SD;
  const float* Wc = a.Wc[cd];
  const float* Wp = a.Wp[cd];
  float part[24];
#pragma unroll
  for (int r = 0; r < 24; ++r) part[r] = 0.f;

  for (int half = 0; half < 2; ++half) {
    __syncthreads();
#pragma unroll
    for (int it = 0; it < 8; ++it) {
      const int f = it * 1024 + t * 4;          // 0..8191
      const int bb = f >> 7, kk = f & 127;
      const float4 v = *(const float4*)(Mp + (long)bb * SD + half * 128 + kk);
      Ms[bb*130 + kk+0] = v.x; Ms[bb*130 + kk+1] = v.y;
      Ms[bb*130 + kk+2] = v.z; Ms[bb*130 + kk+3] = v.w;
    }
    __syncthreads();
    const int kbase = q * 32;
#pragma unroll 2
    for (int k4 = 0; k4 < 8; ++k4) {
      const int kl = kbase + k4 * 4;
      const int kg = half * 128 + kl;
      const float m0 = Ms[b*130 + kl+0], m1 = Ms[b*130 + kl+1];
      const float m2 = Ms[b*130 + kl+2], m3 = Ms[b*130 + kl+3];
#pragma unroll
      for (int c = 0; c < 4; ++c) {
#pragma unroll
        for (int g = 0; g < 3; ++g) {
          const float4 w = *(const float4*)(Wc + (long)(g * SD + j0 + c) * SD + kg);
          part[c*6+g] += m0*w.x + m1*w.y + m2*w.z + m3*w.w;
        }
#pragma unroll
        for (int g = 0; g < 3; ++g) {
          const float4 w = *(const float4*)(Wp + (long)(g * SD + j0 + c) * SD + kg);
          part[c*6+3+g] += m0*w.x + m1*w.y + m2*w.z + m3*w.w;
        }
      }
    }
  }
  __syncthreads();
#pragma unroll
  for (int r = 0; r < 24; ++r) red[(r * 64 + b) * 4 + q] = part[r];
  __syncthreads();

  // finalize: thread -> (col c=q, batch bb=b)
  const int c = q, bb = b, j = j0 + c;
  float s[6];
#pragma unroll
  for (int g = 0; g < 6; ++g) {
    const float4 r4 = *(const float4*)&red[((c*6+g) * 64 + bb) * 4];
    s[g] = (r4.x + r4.y) + (r4.z + r4.w);
  }
  const float ghc_r = s[0] + a.bc[cd][j];
  const float ghc_z = s[1] + a.bc[cd][SD + j];
  const float ghc_n = s[2] + a.bc[cd][2*SD + j];
  const float gip_r = s[3] + a.bp[cd][j];
  const float gip_z = s[4] + a.bp[cd][SD + j];
  const float gip_n = s[5] + a.bp[cd][2*SD + j];
  const long rowT = (long)(i * 64 + bb);
  const long rowC = (long)((i - a.s0) * 64 + bb);
  const float* gk = a.GK[cd] + rowC * 1536;
  const float gic_r = gk[j],       gic_z = gk[256 + j],  gic_n = gk[512 + j];
  const float ghp_r = gk[768 + j], ghp_z = gk[1024 + j], ghp_n = gk[1280 + j];
  const float xj = a.X[cd][rowT * a.ldX + j];
  const float mj = Mp[bb * SD + j];
  // C = gru(x, M): gi precomputed (GK), gh = M@cwhh^T
  const float rC = sigm(gic_r + ghc_r);
  const float zC = sigm(gic_z + ghc_z);
  const float nC = tanhf(gic_n + rC * ghc_n);
  const float Cc = (1.f - zC) * nC + zC * mj;
  // P = gru(M, x): gi = M@pwih^T, gh precomputed (GK)
  const float rP = sigm(gip_r + ghp_r);
  const float zP = sigm(gip_z + ghp_z);
  const float nP = tanhf(gip_n + rP * ghp_n);
  const float Pp = (1.f - zP) * nP + zP * xj;
  a.H1[cd][rowT * SD2 + j] = Cc + Pp;
}

__global__ void zero_k(float* p, long n)
{
  for (long idx = (long)blockIdx.x * 256 + threadIdx.x; idx < n; idx += (long)gridDim.x * 256)
    p[idx] = 0.f;
}

// column means of (8192 x 512), grid (8 colblocks, 32 rowslices), atomicAdd
__global__ void colmean_k(const float* __restrict__ X, float* __restrict__ mean)
{
  __shared__ float red[256];
  const int c = blockIdx.x * 64 + (threadIdx.x & 63), rq = threadIdx.x >> 6;
  const int r0 = blockIdx.y * 256;
  float acc = 0.f;
  for (int r = r0 + rq; r < r0 + 256; r += 4) acc += X[(long)r * SD2 + c];
  red[threadIdx.x] = acc;
  __syncthreads();
  if (threadIdx.x < 64) {
    const float s = red[threadIdx.x] + red[64 + threadIdx.x] + red[128 + threadIdx.x] + red[192 + threadIdx.x];
    atomicAdd(&mean[c], s * (1.f / 8192.f));
  }
}

__global__ void rownorm_k(const float* __restrict__ X, const float* __restrict__ mean,
                          float* __restrict__ inv)
{
  const int r = blockIdx.x * 4 + (threadIdx.x >> 6), lane = threadIdx.x & 63;
  const float* xp = X + (long)r * SD2 + lane * 8;
  const float4 v0 = *(const float4*)xp;
  const float4 v1 = *(const float4*)(xp + 4);
  const float4 m0 = *(const float4*)(mean + lane * 8);
  const float4 m1 = *(const float4*)(mean + lane * 8 + 4);
  float ss = 0.f, d;
  d = v0.x - m0.x; ss += d*d;  d = v0.y - m0.y; ss += d*d;
  d = v0.z - m0.z; ss += d*d;  d = v0.w - m0.w; ss += d*d;
  d = v1.x - m1.x; ss += d*d;  d = v1.y - m1.y; ss += d*d;
  d = v1.z - m1.z; ss += d*d;  d = v1.w - m1.w; ss += d*d;
  ss = wsum(ss);
  if (lane == 0) inv[r] = 1.f / (sqrtf(ss) + 1e-6f);
}

// partial G += xhat^T yhat over K slice; grid (8, 8, 16)
__global__ __launch_bounds__(256)
void gpart_k(const float* __restrict__ X, const float* __restrict__ Y,
             const float* __restrict__ mx, const float* __restrict__ my,
             const float* __restrict__ ix, const float* __restrict__ iy,
             float* __restrict__ G)
{
  __shared__ float As[16][68];
  __shared__ float Bs[16][68];
  __shared__ float mxs[64], mys[64];
  const int t = threadIdx.x, tx = t & 15, ty = t >> 4;
  const int ci = blockIdx.y * 64, cj = blockIdx.x * 64;
  if (t < 64) { mxs[t] = mx[ci + t]; mys[t] = my[cj + t]; }
  float acc[4][4];
#pragma unroll
  for (int ii = 0; ii < 4; ++ii)
#pragma unroll
    for (int jj = 0; jj < 4; ++jj) acc[ii][jj] = 0.f;
  const int rl = t >> 4, c4 = (t & 15) * 4;
  __syncthreads();
  const int kend = blockIdx.z * 512 + 512;
  for (int kb = blockIdx.z * 512; kb < kend; kb += 16) {
    const int r = kb + rl;
    const float4 xv = *(const float4*)(X + (long)r * SD2 + ci + c4);
    const float4 yv = *(const float4*)(Y + (long)r * SD2 + cj + c4);
    const float vx = ix[r], vy = iy[r];
    __syncthreads();
    As[rl][c4+0] = (xv.x - mxs[c4+0]) * vx; As[rl][c4+1] = (xv.y - mxs[c4+1]) * vx;
    As[rl][c4+2] = (xv.z - mxs[c4+2]) * vx; As[rl][c4+3] = (xv.w - mxs[c4+3]) * vx;
    Bs[rl][c4+0] = (yv.x - mys[c4+0]) * vy; Bs[rl][c4+1] = (yv.y - mys[c4+1]) * vy;
    Bs[rl][c4+2] = (yv.z - mys[c4+2]) * vy; Bs[rl][c4+3] = (yv.w - mys[c4+3]) * vy;
    __syncthreads();
#pragma unroll
    for (int kk = 0; kk < 16; ++kk) {
      float av[4], bv[4];
      *(float4*)&av[0] = *(const float4*)&As[kk][ty*4];
      *(float4*)&bv[0] = *(const float4*)&Bs[kk][tx*4];
#pragma unroll
      for (int ii = 0; ii < 4; ++ii)
#pragma unroll
        for (int jj = 0; jj < 4; ++jj)
          acc[ii][jj] = fmaf(av[ii], bv[jj], acc[ii][jj]);
    }
  }
#pragma unroll
  for (int ii = 0; ii < 4; ++ii)
#pragma unroll
    for (int jj = 0; jj < 4; ++jj)
      atomicAdd(&G[(long)(ci + ty*4 + ii) * SD2 + cj + tx*4 + jj], acc[ii][jj]);
}

__global__ void sqsum_k(const float* __restrict__ G, float* __restrict__ dl)
{
  __shared__ float red[4];
  float s = 0.f;
  const long base = (long)blockIdx.x * 1024;
#pragma unroll
  for (int it = 0; it < 4; ++it) { const float v = G[base + it*256 + threadIdx.x]; s += v*v; }
  s = wsum(s);
  const int lane = threadIdx.x & 63, wv = threadIdx.x >> 6;
  if (lane == 0) red[wv] = s;
  __syncthreads();
  if (threadIdx.x == 0) atomicAdd(dl, red[0] + red[1] + red[2] + red[3]);
}

// softmax over rows of length 128 (in-place)
__global__ void smax_k(float* __restrict__ S)
{
  const int r = blockIdx.x * 4 + (threadIdx.x >> 6), lane = threadIdx.x & 63;
  float* p = S + (long)r * SN;
  const float v0 = p[lane], v1 = p[lane + 64];
  float mx = fmaxf(v0, v1);
#pragma unroll
  for (int o = 32; o; o >>= 1) mx = fmaxf(mx, __shfl_xor(mx, o));
  const float e0 = expf(v0 - mx), e1 = expf(v1 - mx);
  float s = e0 + e1;
#pragma unroll
  for (int o = 32; o; o >>= 1) s += __shfl_xor(s, o);
  const float inv = 1.f / s;
  p[lane] = e0 * inv; p[lane + 64] = e1 * inv;
}

__global__ void head_k(const float* __restrict__ H, const float* __restrict__ W,
                       const float* __restrict__ bo, float* __restrict__ out)
{
  const int r = blockIdx.x * 4 + (threadIdx.x >> 6), lane = threadIdx.x & 63;
  const float4 h = *(const float4*)(H + (long)r * SD + lane * 4);
#pragma unroll
  for (int c = 0; c < SNC; ++c) {
    const float4 w = *(const float4*)(W + (long)c * SD + lane * 4);
    float p = h.x*w.x + h.y*w.y + h.z*w.z + h.w*w.w;
    p = wsum(p);
    if (lane == 0) out[(long)r * SNC + c] = p + bo[c];
  }
}

__global__ void fin_k(const float* __restrict__ dl, float* __restrict__ out)
{
  out[0] = (dl[0] + dl[1]) * (0.3f / (512.f * 512.f));
}

// ---------------------------------------------------------------------------
extern "C" void kernel_launch(void* const* d_in, const int* in_sizes, int n_in,
                              void* d_out, int out_size, void* d_ws, size_t ws_size,
                              hipStream_t stream)
{
  (void)in_sizes; (void)n_in; (void)out_size; (void)ws_size;
  const float* F    = (const float*)d_in[0];
  const int*   adj1 = (const int*)  d_in[1];
  const int*   adj2 = (const int*)  d_in[2];
  const float* fc1w = (const float*)d_in[6];
  const float* fc1b = (const float*)d_in[7];
  const float *g_wih[4], *g_whh[4], *g_bih[4], *g_bhh[4];  // gcs, gps, gcl, gpl
  for (int g = 0; g < 4; ++g) {
    g_wih[g] = (const float*)d_in[8 + g*4 + 0];
    g_whh[g] = (const float*)d_in[8 + g*4 + 1];
    g_bih[g] = (const float*)d_in[8 + g*4 + 2];
    g_bhh[g] = (const float*)d_in[8 + g*4 + 3];
  }
  const float* gat_wq[2] = {(const float*)d_in[24], (const float*)d_in[28]};
  const float* gat_bq[2] = {(const float*)d_in[25], (const float*)d_in[29]};
  const float* gat_wk[2] = {(const float*)d_in[26], (const float*)d_in[30]};
  const float* gat_bk[2] = {(const float*)d_in[27], (const float*)d_in[31]};
  const float* aff1 = (const float*)d_in[32];
  const float* aff2 = (const float*)d_in[33];
  const float* mw1  = (const float*)d_in[34];
  const float* mb1  = (const float*)d_in[35];
  const float* mw2  = (const float*)d_in[36];
  const float* mb2  = (const float*)d_in[37];
  const float* ow   = (const float*)d_in[38];
  const float* ob   = (const float*)d_in[39];
  float* out = (float*)d_out;

  // ---- workspace layout (total ~39.7M floats = 152 MB) ----
  float* ws = (float*)d_ws;
  size_t off = 0;
  auto take = [&](size_t nf){ float* p = ws + off; off += nf; return p; };
  float* region = take(22552576);           // overlay region
  float* X0f  = region;                     // 2,097,152 (time-major layer-0 fwd)
  float* X0r  = region + 2097152;           // 2,097,152 (time-major layer-0 bwd)
  float* Qtb  = region + 4194304;           // 4 x 2,097,152
  float* Qtmp = region + 12582912;          // 2,097,152
  float* GKC  = region + 14680064;          // 4 x 1,572,864 (chunk gate precompute)
  float* Htmp = GKC;                        // alias: b-major H0 temp (early only)
  float* Wpk  = region + 20971520;          // 1,572,864
  float* bpk  = region + 22544384;          // 6,144 (+pad)
  // finals overlay (sequential-phase buffers dead by then)
  float* T  = region;                       // 4,194,304
  float* Sb = region + 4194304;             // 1,048,576
  float* HH = region + 5242880;             // 4,194,304
  float* h1 = region + 9437184;             // 2,097,152
  float* h2 = region + 11534336;            // 2,097,152
  float* Ocat[2][2];                        // time-major H1 storage, stride 512
  for (int c = 0; c < 2; ++c) for (int l = 0; l < 2; ++l) Ocat[c][l] = take(4194304);
  float* S0b   = take(32768);               // 4 x 8192
  float* Mbuf  = take(65536);
  float* meanx = take(512);
  float* meany = take(512);
  float* invx  = take(8192);
  float* invy  = take(8192);
  float* dl    = take(8);
  float* Gbuf  = take(262144);

  // H0 = relu(F @ fc1w^T + fc1b)  (b-major temp), then spread to time-major
  gemm_k<false,true,true,false><<<dim3(4,64,1),256,0,stream>>>(
      F, fc1w, fc1b, Htmp, SD, SE, SE, SE, SD, 0,0,0);
  spread_k<<<SBN,256,0,stream>>>(Htmp, X0f, X0r);

  for (int l = 0; l < 2; ++l) {
    PkArgs pk; K1Args k1a; K2Args k2a;
    k1a.M = Mbuf; k2a.M = Mbuf;
    k2a.ldX = l ? SD2 : SD;
    const float* Xarr[4]; int ldX = k2a.ldX;
    for (int cd = 0; cd < 4; ++cd) {
      const int ch = cd >> 1;  // 0 = s-channel, 1 = l-channel
      const float* X = (l == 0) ? ((cd & 1) ? X0r : X0f)
                                : (Ocat[ch][0] + (cd & 1) * SD);
      Xarr[cd] = X;
      const float* wq   = gat_wq[ch] + l * SD * SD;
      const float* bq   = gat_bq[ch] + l * SD;
      const float* wk   = gat_wk[ch] + l * SD * SD;
      const float* bk   = gat_bk[ch] + l * SD;
      const float* cwih = g_wih[ch*2+0] + l * SD3 * SD;
      const float* cwhh = g_whh[ch*2+0] + l * SD3 * SD;
      const float* cbih = g_bih[ch*2+0] + l * SD3;
      const float* cbhh = g_bhh[ch*2+0] + l * SD3;
      const float* pwih = g_wih[ch*2+1] + l * SD3 * SD;
      const float* pwhh = g_whh[ch*2+1] + l * SD3 * SD;
      const float* pbih = g_bih[ch*2+1] + l * SD3;
      const float* pbhh = g_bhh[ch*2+1] + l * SD3;
      pk.wA[cd] = cwih; pk.wB[cd] = pwhh; pk.bA[cd] = cbih; pk.bB[cd] = pbhh;
      // Qtmp = X@wq^T + bq ; Qt = Qtmp@wk ; S0 = Qtmp . bk
      gemm_k<false,true,false,false><<<dim3(4,64,1),256,0,stream>>>(
          X, wq, bq, Qtmp, SD, SD, ldX, SD, SD, 0,0,0);
      gemm_k<true,false,false,false><<<dim3(4,64,1),256,0,stream>>>(
          Qtmp, wk, nullptr, Qtb + (size_t)cd*2097152, SD, SD, SD, SD, SD, 0,0,0);
      s0_k<<<SBN/4,256,0,stream>>>(Qtmp, bk, S0b + cd*SBN);
      float* H1mut = Ocat[ch][l] + (cd & 1) * SD;
      k1a.Qt[cd] = Qtb + (size_t)cd*2097152;
      k1a.S0[cd] = S0b + cd*SBN;
      k1a.H1[cd] = H1mut;
      k1a.adj[cd] = ch ? adj2 : adj1; k1a.rev[cd] = cd & 1;
      k2a.Wc[cd] = cwhh; k2a.Wp[cd] = pwih; k2a.bc[cd] = cbhh; k2a.bp[cd] = pbih;
      k2a.GK[cd] = GKC + (size_t)cd*1572864;
      k2a.X[cd] = X; k2a.H1[cd] = H1mut;
    }
    pk.Wpk = Wpk; pk.bpk = bpk;
    pack_k<<<dim3(1536,4),256,0,stream>>>(pk);

    for (int s0 = 0; s0 < SN; s0 += CS) {
      // gate precompute for chunk: GKC[cd] = X[rows s0*64 .. +1024) @ Wpk^T + bpk
      for (int cd = 0; cd < 4; ++cd)
        gemm_k<false,true,false,false><<<dim3(24,8,1),256,0,stream>>>(
            Xarr[cd] + (long)s0*64*ldX, Wpk + (size_t)cd*1536*SD, bpk + cd*1536,
            GKC + (size_t)cd*1572864, 1536, SD, ldX, SD, 1536, 0,0,0);
      for (int i = s0; i < s0 + CS; ++i) {
        k1a.step = i;
        k1_attn<<<256,256,0,stream>>>(k1a);
        k2a.step = i; k2a.s0 = s0;
        k2_gates<<<dim3(64,4,1),256,0,stream>>>(k2a);
      }
    }
  }

  // diff loss (row-permutation invariant -> time-major OK)
  zero_k<<<1,256,0,stream>>>(dl, 2);
  for (int l = 0; l < 2; ++l) {
    zero_k<<<4,256,0,stream>>>(meanx, 1024);  // meanx+meany contiguous
    colmean_k<<<dim3(8,32,1),256,0,stream>>>(Ocat[0][l], meanx);
    colmean_k<<<dim3(8,32,1),256,0,stream>>>(Ocat[1][l], meany);
    rownorm_k<<<SBN/4,256,0,stream>>>(Ocat[0][l], meanx, invx);
    rownorm_k<<<SBN/4,256,0,stream>>>(Ocat[1][l], meany, invy);
    zero_k<<<256,256,0,stream>>>(Gbuf, (long)SD2*SD2);
    gpart_k<<<dim3(8,8,16),256,0,stream>>>(Ocat[0][l], Ocat[1][l], meanx, meany, invx, invy, Gbuf);
    sqsum_k<<<256,256,0,stream>>>(Gbuf, dl + l);
  }

  // cross attention + final MLP (h1 accumulated from F / HSn / HLn slices)
  // T1 = HS@aff1 ; S = T1@HL^T ; softmax ; HSn = S@HL (b-major out)
  gemm_k<true,false,false,false><<<dim3(8,64,1),256,0,stream>>>(
      Ocat[0][1], aff1, nullptr, T, SD2, SD2, SD2, SD2, SD2, 0,0,0);
  gemm_k<false,false,false,false><<<dim3(2,1,64),256,0,stream>>>(
      T, Ocat[1][1], nullptr, Sb, SN, SD2, 64*SD2, 64*SD2, SN, SD2, SD2, (long)SN*SN);
  smax_k<<<SBN/4,256,0,stream>>>(Sb);
  gemm_k<true,false,false,false><<<dim3(8,1,64),256,0,stream>>>(
      Sb, Ocat[1][1], nullptr, HH, SD2, SN, SN, 64*SD2, SD2, (long)SN*SN, SD2, (long)SN*SD2);
  gemm_k<false,true,false,false><<<dim3(4,64,1),256,0,stream>>>(
      F, mw1, mb1, h1, SD, SE, SE, SIN, SD, 0,0,0);
  gemm_k<false,false,false,true><<<dim3(4,64,1),256,0,stream>>>(
      HH, mw1 + 1024, nullptr, h1, SD, SD2, SD2, SIN, SD, 0,0,0);
  // T2 = HL@aff2 ; S = T2@HS^T ; softmax ; HLn = S@HS (b-major out)
  gemm_k<true,false,false,false><<<dim3(8,64,1),256,0,stream>>>(
      Ocat[1][1], aff2, nullptr, T, SD2, SD2, SD2, SD2, SD2, 0,0,0);
  gemm_k<false,false,false,false><<<dim3(2,1,64),256,0,stream>>>(
      T, Ocat[0][1], nullptr, Sb, SN, SD2, 64*SD2, 64*SD2, SN, SD2, SD2, (long)SN*SN);
  smax_k<<<SBN/4,256,0,stream>>>(Sb);
  gemm_k<true,false,false,false><<<dim3(8,1,64),256,0,stream>>>(
      Sb, Ocat[0][1], nullptr, HH, SD2, SN, SN, 64*SD2, SD2, (long)SN*SN, SD2, (long)SN*SD2);
  gemm_k<false,false,true,true><<<dim3(4,64,1),256,0,stream>>>(
      HH, mw1 + 1536, nullptr, h1, SD, SD2, SD2, SIN, SD, 0,0,0);
  gemm_k<false,true,true,false><<<dim3(4,64,1),256,0,stream>>>(
      h1, mw2, mb2, h2, SD, SD, SD, SD, SD, 0,0,0);
  head_k<<<SBN/4,256,0,stream>>>(h2, ow, ob, out);
  fin_k<<<1,1,0,stream>>>(dl, out + SBN * SNC);
}